// Round 1
// baseline (2117.833 us; speedup 1.0000x reference)
//
#include <hip/hip_runtime.h>
#include <math.h>

// SpectralAttention on gfx950 — round 1: correctness-first, f64-armored softmax path.
// B=2, T=2048, C=1024, H=16, HD=64.
//
// ws layout (floats):
//   qT  [0,        4M)   : q transposed [b][c][t]; after FFT holds 0.125*Re(qf)
//   kT  [4M,       8M)   : k transposed; after FFT holds Re(kf)
//   vT  [8M,      12M)   : v transposed; after FFT holds Re(vf)
//   qiT [12M,     16M)   : 0.125*Im(qf)
//   kiT [16M,     20M)   : -Im(kf)   (negated so S-GEMM is a single K=128 dot)
//   att [20M,     24M)   : attended [b*t][h*hd]
//   tw  at 24M floats    : double2[1024] FFT twiddles
//   filt tw+16KB         : float2[2048] spectral filter (cos,sin)
// total: 96MB + 32KB

#define T_ 2048
#define C_ 1024

// ---------------------------------------------------------------- init tables
__global__ __launch_bounds__(256) void k_init_tables(
    double2* __restrict__ tw, float2* __restrict__ filt,
    const float* __restrict__ fd, const float* __restrict__ alpha,
    const float* __restrict__ fas)
{
    int i = blockIdx.x * 256 + threadIdx.x;   // grid 8*256 = 2048
    double aa = (double)alpha[0] + (double)fas[0] * ((double)fd[0] - 1.5);
    if (i < 1024) {
        double ang = -2.0 * 3.14159265358979323846 * (double)i / 2048.0;
        double s, c;
        sincos(ang, &s, &c);
        tw[i] = make_double2(c, s);
    }
    if (i < 2048) {
        double fr = (i < 1024) ? (double)i / 2048.0 : ((double)i - 2048.0) / 2048.0;
        double ph = aa * atan(log(fabs(fr) + 1e-10));
        double s, c;
        sincos(ph, &s, &c);
        filt[i] = make_float2((float)c, (float)s);
    }
}

// ------------------------------------------------------------- QKV GEMM (f64 acc)
// x[4096,1024] @ {wq,wk,wv}[1024,1024] + bias -> transposed out[b][c][t]
__global__ __launch_bounds__(256) void k_qkv_gemm(
    const float* __restrict__ x,
    const float* __restrict__ wq, const float* __restrict__ bq,
    const float* __restrict__ wk, const float* __restrict__ bk,
    const float* __restrict__ wv, const float* __restrict__ bv,
    float* __restrict__ qT, float* __restrict__ kT, float* __restrict__ vT)
{
    __shared__ float As[16][64];
    __shared__ float Bs[16][64];
    const int tid = threadIdx.x;
    const int tx = tid & 15, ty = tid >> 4;
    const int tx4 = tx * 4, ty4 = ty * 4;
    const int m0 = blockIdx.x * 64;
    const int nb = blockIdx.y;                  // 0..47
    const int mat = nb >> 4;
    const int n0 = (nb & 15) * 64;
    const float* W    = (mat == 0) ? wq : (mat == 1) ? wk : wv;
    const float* bias = (mat == 0) ? bq : (mat == 1) ? bk : bv;
    float* outp       = (mat == 0) ? qT : (mat == 1) ? kT : vT;

    const int am = tid >> 2, ak = (tid & 3) * 4;      // A tile 64m x 16k
    const int bkr = tid >> 4, bn = (tid & 15) * 4;    // B tile 16k x 64n

    double acc[4][4];
#pragma unroll
    for (int i = 0; i < 4; ++i)
#pragma unroll
        for (int j = 0; j < 4; ++j) acc[i][j] = 0.0;

    for (int k0 = 0; k0 < 1024; k0 += 16) {
        __syncthreads();
        float4 av = *(const float4*)&x[(size_t)(m0 + am) * 1024 + k0 + ak];
        As[ak + 0][am] = av.x; As[ak + 1][am] = av.y;
        As[ak + 2][am] = av.z; As[ak + 3][am] = av.w;
        *(float4*)&Bs[bkr][bn] = *(const float4*)&W[(size_t)(k0 + bkr) * 1024 + n0 + bn];
        __syncthreads();
#pragma unroll
        for (int kk = 0; kk < 16; ++kk) {
            float4 a = *(const float4*)&As[kk][ty4];
            float4 b = *(const float4*)&Bs[kk][tx4];
            double ar[4] = {(double)a.x, (double)a.y, (double)a.z, (double)a.w};
            double br[4] = {(double)b.x, (double)b.y, (double)b.z, (double)b.w};
#pragma unroll
            for (int i = 0; i < 4; ++i)
#pragma unroll
                for (int j = 0; j < 4; ++j)
                    acc[i][j] = fma(ar[i], br[j], acc[i][j]);
        }
    }
    float4 bb = *(const float4*)&bias[n0 + tx4];
    float bbv[4] = {bb.x, bb.y, bb.z, bb.w};
    const int b_ = m0 >> 11;                // /2048
    const int tloc = (m0 & 2047) + ty4;
#pragma unroll
    for (int j = 0; j < 4; ++j) {
        int cg = n0 + tx4 + j;
        float4 w = make_float4((float)acc[0][j] + bbv[j], (float)acc[1][j] + bbv[j],
                               (float)acc[2][j] + bbv[j], (float)acc[3][j] + bbv[j]);
        *(float4*)&outp[((size_t)(b_ * 1024 + cg)) * 2048 + tloc] = w;
    }
}

// ------------------------------------------------------------- FFT + filter (f64)
// one block per (mat, b, c) sequence; radix-2 DIT in LDS, bit-reversed load.
__global__ __launch_bounds__(256) void k_fft_filter(
    float* __restrict__ qT, float* __restrict__ kT, float* __restrict__ vT,
    float* __restrict__ qiT, float* __restrict__ kiT,
    const double2* __restrict__ tw, const float2* __restrict__ filt)
{
    __shared__ double2 sf[2048];
    const int bid = blockIdx.x;          // 0..6143
    const int mat = bid >> 11;
    const int seq = bid & 2047;          // b*1024 + c
    float* base = (mat == 0) ? qT : (mat == 1) ? kT : vT;
    float* src = base + (size_t)seq * 2048;
    const int tid = threadIdx.x;

    for (int i = tid; i < 2048; i += 256) {
        int j = (int)(__brev((unsigned)i) >> 21);
        sf[j] = make_double2((double)src[i], 0.0);
    }
    __syncthreads();
    for (int st = 1; st <= 11; ++st) {
        const int len = 1 << st, half = len >> 1;
        const int shift = 11 - st;
        for (int u = tid; u < 1024; u += 256) {
            int pos = u & (half - 1);
            int bi = 2 * u - pos;
            double2 w = tw[pos << shift];
            double2 a = sf[bi], b = sf[bi + half];
            double tr = w.x * b.x - w.y * b.y;
            double ti = w.x * b.y + w.y * b.x;
            sf[bi]        = make_double2(a.x + tr, a.y + ti);
            sf[bi + half] = make_double2(a.x - tr, a.y - ti);
        }
        __syncthreads();
    }
    for (int i = tid; i < 2048; i += 256) {
        double2 z = sf[i];
        float2 f = filt[i];
        double c = (double)f.x, s = (double)f.y;
        double re = z.x * c - z.y * s;
        double im = z.x * s + z.y * c;
        if (mat == 0) {
            src[i] = (float)(0.125 * re);                       // fold 1/sqrt(64)
            qiT[(size_t)seq * 2048 + i] = (float)(0.125 * im);
        } else if (mat == 1) {
            src[i] = (float)re;
            kiT[(size_t)seq * 2048 + i] = (float)(-im);          // fold the minus sign
        } else {
            src[i] = (float)re;                                  // Re(vf) only
        }
    }
}

// ------------------------------------------------------------- flash attention
// one block per (b,h, t-tile of 64). S accumulated in f64; exp/PV in f32.
__global__ __launch_bounds__(256) void k_flash(
    const float* __restrict__ qT, const float* __restrict__ qiT,
    const float* __restrict__ kT, const float* __restrict__ kiT,
    const float* __restrict__ vT, float* __restrict__ att)
{
    __shared__ float Qc[128 * 64];     // 32KB [d(0..63 re,64..127 im)][t]
    __shared__ float KV[128 * 64];     // 32KB: K tile; then V (rows 0..63) + P (rows 64..127)
    const int tid = threadIdx.x;
    const int tx = tid & 15, ty = tid >> 4;
    const int tx4 = tx * 4, ty4 = ty * 4;
    const int bid = blockIdx.x;
    const int t0 = (bid & 31) * 64;
    const int bh = bid >> 5;                   // b*16 + h
    const size_t bc = (size_t)bh * 64;         // = b*1024 + h*64

#pragma unroll
    for (int ch = 0; ch < 8; ++ch) {
        int e = tid * 4 + ch * 1024;
        int r = e >> 6, col = e & 63;
        const float* p = (r < 64) ? (qT + (bc + r) * 2048 + t0 + col)
                                  : (qiT + (bc + r - 64) * 2048 + t0 + col);
        *(float4*)&Qc[r * 64 + col] = *(const float4*)p;
    }

    double S[4][4];
    float O[4][4] = {{0.f}};
    double mrow[4] = {-1e300, -1e300, -1e300, -1e300};
    float lrow[4] = {0.f, 0.f, 0.f, 0.f};

    for (int s0 = 0; s0 < 2048; s0 += 64) {
        __syncthreads();                        // prior PV / P reads done
#pragma unroll
        for (int ch = 0; ch < 8; ++ch) {
            int e = tid * 4 + ch * 1024;
            int r = e >> 6, col = e & 63;
            const float* p = (r < 64) ? (kT + (bc + r) * 2048 + s0 + col)
                                      : (kiT + (bc + r - 64) * 2048 + s0 + col);
            *(float4*)&KV[r * 64 + col] = *(const float4*)p;
        }
        __syncthreads();

#pragma unroll
        for (int i = 0; i < 4; ++i)
#pragma unroll
            for (int j = 0; j < 4; ++j) S[i][j] = 0.0;

#pragma unroll 4
        for (int d = 0; d < 128; ++d) {
            float4 a = *(const float4*)&Qc[d * 64 + ty4];
            float4 b = *(const float4*)&KV[d * 64 + tx4];
            double ar[4] = {(double)a.x, (double)a.y, (double)a.z, (double)a.w};
            double br[4] = {(double)b.x, (double)b.y, (double)b.z, (double)b.w};
#pragma unroll
            for (int i = 0; i < 4; ++i)
#pragma unroll
                for (int j = 0; j < 4; ++j)
                    S[i][j] = fma(ar[i], br[j], S[i][j]);
        }

        float pf[4][4];
#pragma unroll
        for (int i = 0; i < 4; ++i) {
            double mt = fmax(fmax(S[i][0], S[i][1]), fmax(S[i][2], S[i][3]));
#pragma unroll
            for (int msk = 1; msk < 16; msk <<= 1)
                mt = fmax(mt, __shfl_xor(mt, msk, 16));
            double mn = fmax(mrow[i], mt);
            float al = __expf((float)(mrow[i] - mn));
            mrow[i] = mn;
            float rs = 0.f;
#pragma unroll
            for (int j = 0; j < 4; ++j) {
                float pv = __expf((float)(S[i][j] - mn));
                pf[i][j] = pv;
                rs += pv;
            }
#pragma unroll
            for (int msk = 1; msk < 16; msk <<= 1)
                rs += __shfl_xor(rs, msk, 16);
            lrow[i] = lrow[i] * al + rs;
#pragma unroll
            for (int j = 0; j < 4; ++j) O[i][j] *= al;
        }

        __syncthreads();                       // done reading K from KV
        // V transposed into KV rows 0..63 as Vs[s][d]; P into rows 64..127
#pragma unroll
        for (int ch = 0; ch < 4; ++ch) {
            int e = tid * 4 + ch * 1024;
            int d = e >> 6, sc = e & 63;
            float4 vv = *(const float4*)&vT[(bc + d) * 2048 + s0 + sc];
            KV[(sc + 0) * 64 + d] = vv.x;
            KV[(sc + 1) * 64 + d] = vv.y;
            KV[(sc + 2) * 64 + d] = vv.z;
            KV[(sc + 3) * 64 + d] = vv.w;
        }
        float* Ps = &KV[4096];
#pragma unroll
        for (int i = 0; i < 4; ++i)
            *(float4*)&Ps[(ty4 + i) * 64 + tx4] =
                make_float4(pf[i][0], pf[i][1], pf[i][2], pf[i][3]);
        __syncthreads();

#pragma unroll 8
        for (int s = 0; s < 64; ++s) {
            float4 vv = *(const float4*)&KV[s * 64 + tx4];
            float pr[4] = {Ps[(ty4 + 0) * 64 + s], Ps[(ty4 + 1) * 64 + s],
                           Ps[(ty4 + 2) * 64 + s], Ps[(ty4 + 3) * 64 + s]};
            float vr[4] = {vv.x, vv.y, vv.z, vv.w};
#pragma unroll
            for (int i = 0; i < 4; ++i)
#pragma unroll
                for (int j = 0; j < 4; ++j)
                    O[i][j] = fmaf(pr[i], vr[j], O[i][j]);
        }
    }

    const int b = bh >> 4, h = bh & 15;
#pragma unroll
    for (int i = 0; i < 4; ++i) {
        float inv = 1.0f / lrow[i];
        float4 w = make_float4(O[i][0] * inv, O[i][1] * inv, O[i][2] * inv, O[i][3] * inv);
        size_t row = (size_t)b * 2048 + t0 + ty4 + i;
        *(float4*)&att[row * 1024 + h * 64 + tx4] = w;
    }
}

// ------------------------------------------------------------- output GEMM (f32)
__global__ __launch_bounds__(256) void k_out_gemm(
    const float* __restrict__ att, const float* __restrict__ wo,
    const float* __restrict__ bo, float* __restrict__ out)
{
    __shared__ float As[16][64];
    __shared__ float Bs[16][64];
    const int tid = threadIdx.x;
    const int tx = tid & 15, ty = tid >> 4;
    const int tx4 = tx * 4, ty4 = ty * 4;
    const int m0 = blockIdx.x * 64;
    const int n0 = blockIdx.y * 64;
    const int am = tid >> 2, ak = (tid & 3) * 4;
    const int bkr = tid >> 4, bn = (tid & 15) * 4;

    float acc[4][4] = {{0.f}};
    for (int k0 = 0; k0 < 1024; k0 += 16) {
        __syncthreads();
        float4 av = *(const float4*)&att[(size_t)(m0 + am) * 1024 + k0 + ak];
        As[ak + 0][am] = av.x; As[ak + 1][am] = av.y;
        As[ak + 2][am] = av.z; As[ak + 3][am] = av.w;
        *(float4*)&Bs[bkr][bn] = *(const float4*)&wo[(size_t)(k0 + bkr) * 1024 + n0 + bn];
        __syncthreads();
#pragma unroll
        for (int kk = 0; kk < 16; ++kk) {
            float4 a = *(const float4*)&As[kk][ty4];
            float4 b = *(const float4*)&Bs[kk][tx4];
            float ar[4] = {a.x, a.y, a.z, a.w};
            float br[4] = {b.x, b.y, b.z, b.w};
#pragma unroll
            for (int i = 0; i < 4; ++i)
#pragma unroll
                for (int j = 0; j < 4; ++j)
                    acc[i][j] = fmaf(ar[i], br[j], acc[i][j]);
        }
    }
    float4 bb = *(const float4*)&bo[n0 + tx4];
#pragma unroll
    for (int i = 0; i < 4; ++i) {
        float4 w = make_float4(acc[i][0] + bb.x, acc[i][1] + bb.y,
                               acc[i][2] + bb.z, acc[i][3] + bb.w);
        *(float4*)&out[(size_t)(m0 + ty4 + i) * 1024 + n0 + tx4] = w;
    }
}

// ------------------------------------------------------------- energy renorm
__global__ __launch_bounds__(256) void k_norm(
    const float* __restrict__ x, float* __restrict__ out,
    const float* __restrict__ en)
{
    const int row = blockIdx.x;
    const int tid = threadIdx.x;
    const float* xr = x + (size_t)row * 1024;
    float* orow = out + (size_t)row * 1024;
    float4 xv = *(const float4*)&xr[tid * 4];
    float4 ov = *(const float4*)&orow[tid * 4];
    float ssx = xv.x * xv.x + xv.y * xv.y + xv.z * xv.z + xv.w * xv.w;
    float sso = ov.x * ov.x + ov.y * ov.y + ov.z * ov.z + ov.w * ov.w;
#pragma unroll
    for (int m = 1; m <= 32; m <<= 1) {
        ssx += __shfl_xor(ssx, m, 64);
        sso += __shfl_xor(sso, m, 64);
    }
    __shared__ float rx[4], ro[4];
    const int wid = tid >> 6;
    if ((tid & 63) == 0) { rx[wid] = ssx; ro[wid] = sso; }
    __syncthreads();
    float tsx = rx[0] + rx[1] + rx[2] + rx[3];
    float tso = ro[0] + ro[1] + ro[2] + ro[3];
    float scale = sqrtf(tsx) / (sqrtf(tso) + 1e-8f) * en[0];
    ov.x *= scale; ov.y *= scale; ov.z *= scale; ov.w *= scale;
    *(float4*)&orow[tid * 4] = ov;
}

// ------------------------------------------------------------- launch
extern "C" void kernel_launch(void* const* d_in, const int* in_sizes, int n_in,
                              void* d_out, int out_size, void* d_ws, size_t ws_size,
                              hipStream_t stream)
{
    const float* x     = (const float*)d_in[0];
    const float* fd    = (const float*)d_in[1];
    const float* wq    = (const float*)d_in[2];
    const float* bq    = (const float*)d_in[3];
    const float* wk    = (const float*)d_in[4];
    const float* bk    = (const float*)d_in[5];
    const float* wv    = (const float*)d_in[6];
    const float* bv    = (const float*)d_in[7];
    const float* wo    = (const float*)d_in[8];
    const float* bo    = (const float*)d_in[9];
    const float* alpha = (const float*)d_in[10];
    const float* fas   = (const float*)d_in[11];
    const float* en    = (const float*)d_in[12];
    float* out = (float*)d_out;
    float* ws  = (float*)d_ws;

    float* qT  = ws;
    float* kT  = ws + (size_t)1 * 4194304;
    float* vT  = ws + (size_t)2 * 4194304;
    float* qiT = ws + (size_t)3 * 4194304;
    float* kiT = ws + (size_t)4 * 4194304;
    float* att = ws + (size_t)5 * 4194304;
    double2* tw  = (double2*)(ws + (size_t)6 * 4194304);
    float2* filt = (float2*)(ws + (size_t)6 * 4194304 + 4096);

    k_init_tables<<<8, 256, 0, stream>>>(tw, filt, fd, alpha, fas);
    k_qkv_gemm<<<dim3(64, 48), 256, 0, stream>>>(x, wq, bq, wk, bk, wv, bv, qT, kT, vT);
    k_fft_filter<<<6144, 256, 0, stream>>>(qT, kT, vT, qiT, kiT, tw, filt);
    k_flash<<<1024, 256, 0, stream>>>(qT, qiT, kT, kiT, vT, att);
    k_out_gemm<<<dim3(64, 16), 256, 0, stream>>>(att, wo, bo, out);
    k_norm<<<4096, 256, 0, stream>>>(x, out, en);
}

// Round 2
// 1512.466 us; speedup vs baseline: 1.4003x; 1.4003x over previous
//
#include <hip/hip_runtime.h>
#include <math.h>

// SpectralAttention gfx950 — round 2: all-fp32 compute (f64 only in table init).
// B=2, T=2048, C=1024, H=16, HD=64.
//
// ws layout (floats):
//   qT  [0,    4M) : [b][c][t]; after FFT holds 0.125*Re(qf)
//   kT  [4M,   8M) : after FFT holds Re(kf)
//   vT  [8M,  12M) : after FFT holds Re(vf)
//   qiT [12M, 16M) : 0.125*Im(qf)
//   kiT [16M, 20M) : -Im(kf)  (negated: S = sum over 128 dims, one GEMM)
//   att [20M, 24M) : attended [b*t][c]
//   tw  at 24M     : float2[1024] FFT twiddles
//   filt +2048 f32 : float2[2048] spectral filter
// total 96 MB + 16 KB

// ---------------------------------------------------------------- init tables
__global__ __launch_bounds__(256) void k_init_tables(
    float2* __restrict__ tw, float2* __restrict__ filt,
    const float* __restrict__ fd, const float* __restrict__ alpha,
    const float* __restrict__ fas)
{
    int i = blockIdx.x * 256 + threadIdx.x;   // grid 8*256 = 2048
    double aa = (double)alpha[0] + (double)fas[0] * ((double)fd[0] - 1.5);
    if (i < 1024) {
        double ang = -2.0 * 3.14159265358979323846 * (double)i / 2048.0;
        double s, c;
        sincos(ang, &s, &c);
        tw[i] = make_float2((float)c, (float)s);
    }
    if (i < 2048) {
        double fr = (i < 1024) ? (double)i / 2048.0 : ((double)i - 2048.0) / 2048.0;
        double ph = aa * atan(log(fabs(fr) + 1e-10));
        double s, c;
        sincos(ph, &s, &c);
        filt[i] = make_float2((float)c, (float)s);
    }
}

// ------------------------------------------------------------- QKV GEMM (f32)
// Computes C^T = W^T X^T directly: out[c][t], 128x128 tile, 8x8 micro/lane.
__global__ __launch_bounds__(256) void k_qkv_gemm(
    const float* __restrict__ x,
    const float* __restrict__ wq, const float* __restrict__ bq,
    const float* __restrict__ wk, const float* __restrict__ bk,
    const float* __restrict__ wv, const float* __restrict__ bv,
    float* __restrict__ qT, float* __restrict__ kT, float* __restrict__ vT)
{
    __shared__ __align__(16) float As[16][128];   // As[k][m] = x[m0+m][k0+k]
    __shared__ __align__(16) float Bs[16][128];   // Bs[k][n] = W[k0+k][n0+n]
    const int tid = threadIdx.x;
    const int mat = blockIdx.z;
    const float* W    = (mat == 0) ? wq : (mat == 1) ? wk : wv;
    const float* bias = (mat == 0) ? bq : (mat == 1) ? bk : bv;
    float* outp       = (mat == 0) ? qT : (mat == 1) ? kT : vT;
    const int m0 = blockIdx.x * 128, n0 = blockIdx.y * 128;
    const int am = tid >> 1, ak = (tid & 1) * 8;      // A stage: 128m x 16k
    const int bkr = tid >> 4, bn = (tid & 15) * 8;    // B stage: 16k x 128n
    const int tx = tid & 15, ty = tid >> 4;           // micro: ty->n(8), tx->m(8)

    const float* ax = &x[(size_t)(m0 + am) * 1024 + ak];
    const float* bw = &W[(size_t)bkr * 1024 + n0 + bn];
    float4 pa0 = *(const float4*)ax, pa1 = *(const float4*)(ax + 4);
    float4 pb0 = *(const float4*)bw, pb1 = *(const float4*)(bw + 4);

    float acc[8][8] = {};
    for (int k0 = 0; k0 < 1024; k0 += 16) {
        __syncthreads();
        As[ak + 0][am] = pa0.x; As[ak + 1][am] = pa0.y;
        As[ak + 2][am] = pa0.z; As[ak + 3][am] = pa0.w;
        As[ak + 4][am] = pa1.x; As[ak + 5][am] = pa1.y;
        As[ak + 6][am] = pa1.z; As[ak + 7][am] = pa1.w;
        *(float4*)&Bs[bkr][bn] = pb0;
        *(float4*)&Bs[bkr][bn + 4] = pb1;
        __syncthreads();
        if (k0 < 1008) {
            const float* ax2 = &x[(size_t)(m0 + am) * 1024 + k0 + 16 + ak];
            pa0 = *(const float4*)ax2; pa1 = *(const float4*)(ax2 + 4);
            const float* bw2 = &W[(size_t)(k0 + 16 + bkr) * 1024 + n0 + bn];
            pb0 = *(const float4*)bw2; pb1 = *(const float4*)(bw2 + 4);
        }
#pragma unroll
        for (int kk = 0; kk < 16; ++kk) {
            float4 w0 = *(const float4*)&Bs[kk][ty * 8];
            float4 w1 = *(const float4*)&Bs[kk][ty * 8 + 4];
            float4 x0 = *(const float4*)&As[kk][tx * 8];
            float4 x1 = *(const float4*)&As[kk][tx * 8 + 4];
            float wr[8] = {w0.x, w0.y, w0.z, w0.w, w1.x, w1.y, w1.z, w1.w};
            float xr[8] = {x0.x, x0.y, x0.z, x0.w, x1.x, x1.y, x1.z, x1.w};
#pragma unroll
            for (int i = 0; i < 8; ++i)
#pragma unroll
                for (int j = 0; j < 8; ++j)
                    acc[i][j] = fmaf(wr[i], xr[j], acc[i][j]);
        }
    }
    const int b_ = m0 >> 11;
    const int tbase = (m0 & 2047) + tx * 8;
#pragma unroll
    for (int i = 0; i < 8; ++i) {
        int n = n0 + ty * 8 + i;                 // channel
        float bv_ = bias[n];
        float4 o0 = make_float4(acc[i][0] + bv_, acc[i][1] + bv_,
                                acc[i][2] + bv_, acc[i][3] + bv_);
        float4 o1 = make_float4(acc[i][4] + bv_, acc[i][5] + bv_,
                                acc[i][6] + bv_, acc[i][7] + bv_);
        float* op = &outp[((size_t)(b_ * 1024 + n)) * 2048 + tbase];
        *(float4*)op = o0;
        *(float4*)(op + 4) = o1;
    }
}

// ------------------------------------------------------------- FFT + filter (f32)
__global__ __launch_bounds__(256) void k_fft_filter(
    float* __restrict__ qT, float* __restrict__ kT, float* __restrict__ vT,
    float* __restrict__ qiT, float* __restrict__ kiT,
    const float2* __restrict__ tw, const float2* __restrict__ filt)
{
    __shared__ float2 sf[2048];
    const int bid = blockIdx.x;          // 0..6143
    const int mat = bid >> 11;
    const int seq = bid & 2047;
    float* base = (mat == 0) ? qT : (mat == 1) ? kT : vT;
    float* src = base + (size_t)seq * 2048;
    const int tid = threadIdx.x;

    for (int i = tid; i < 2048; i += 256) {
        int j = (int)(__brev((unsigned)i) >> 21);
        sf[j] = make_float2(src[i], 0.f);
    }
    __syncthreads();
    for (int st = 1; st <= 11; ++st) {
        const int half = 1 << (st - 1);
        const int shift = 11 - st;
        for (int u = tid; u < 1024; u += 256) {
            int pos = u & (half - 1);
            int bi = 2 * u - pos;
            float2 w = tw[pos << shift];
            float2 a = sf[bi], b = sf[bi + half];
            float tr = w.x * b.x - w.y * b.y;
            float ti = w.x * b.y + w.y * b.x;
            sf[bi]        = make_float2(a.x + tr, a.y + ti);
            sf[bi + half] = make_float2(a.x - tr, a.y - ti);
        }
        __syncthreads();
    }
    for (int i = tid; i < 2048; i += 256) {
        float2 z = sf[i];
        float2 f = filt[i];
        float re = z.x * f.x - z.y * f.y;
        float im = z.x * f.y + z.y * f.x;
        if (mat == 0) {
            src[i] = 0.125f * re;                       // fold 1/sqrt(64)
            qiT[(size_t)seq * 2048 + i] = 0.125f * im;
        } else if (mat == 1) {
            src[i] = re;
            kiT[(size_t)seq * 2048 + i] = -im;           // fold minus sign
        } else {
            src[i] = re;
        }
    }
}

// ------------------------------------------------------------- flash attention (f32)
// block = (b,h, 64 t-rows). t64 x s64 tiles, 4x4 micro. LDS exactly 64 KB.
// V stored in LDS with XOR-rotate: phys(s,d) = s*64 + ((d + (s&60)) & 63)
// -> both transpose-stores and PV-reads are 2-way (free).
__global__ __launch_bounds__(256) void k_flash(
    const float* __restrict__ qT, const float* __restrict__ qiT,
    const float* __restrict__ kT, const float* __restrict__ kiT,
    const float* __restrict__ vT, float* __restrict__ att)
{
    __shared__ __align__(16) float Qc[8192];   // [d 0..127][t 0..63]
    __shared__ __align__(16) float KV[8192];   // K [128][64]; then Vs(rot)[0..4095] + Ps[4096..]
    float* Ps = &KV[4096];
    const int tid = threadIdx.x;
    const int tx = tid & 15, ty = tid >> 4;
    const int tx4 = tx * 4, ty4 = ty * 4;
    const int bid = blockIdx.x;
    const int t0 = (bid & 31) * 64;
    const int bh = bid >> 5;
    const size_t bc = (size_t)bh * 64;

#pragma unroll
    for (int ch = 0; ch < 8; ++ch) {
        int e = tid * 4 + ch * 1024;
        int r = e >> 6, col = e & 63;
        const float* p = (r < 64) ? (qT + (bc + r) * 2048 + t0 + col)
                                  : (qiT + (bc + r - 64) * 2048 + t0 + col);
        *(float4*)&Qc[r * 64 + col] = *(const float4*)p;
    }

    float S[4][4];
    float O[4][4] = {{0.f}};
    float mrow[4] = {-3e38f, -3e38f, -3e38f, -3e38f};
    float lrow[4] = {0.f, 0.f, 0.f, 0.f};

    for (int s0 = 0; s0 < 2048; s0 += 64) {
        __syncthreads();                        // prior PV reads done
#pragma unroll
        for (int ch = 0; ch < 8; ++ch) {
            int e = tid * 4 + ch * 1024;
            int r = e >> 6, col = e & 63;
            const float* p = (r < 64) ? (kT + (bc + r) * 2048 + s0 + col)
                                      : (kiT + (bc + r - 64) * 2048 + s0 + col);
            *(float4*)&KV[r * 64 + col] = *(const float4*)p;
        }
        __syncthreads();

#pragma unroll
        for (int i = 0; i < 4; ++i)
#pragma unroll
            for (int j = 0; j < 4; ++j) S[i][j] = 0.f;

#pragma unroll 8
        for (int d = 0; d < 128; ++d) {
            float4 a = *(const float4*)&Qc[d * 64 + ty4];
            float4 b = *(const float4*)&KV[d * 64 + tx4];
            float ar[4] = {a.x, a.y, a.z, a.w};
            float br[4] = {b.x, b.y, b.z, b.w};
#pragma unroll
            for (int i = 0; i < 4; ++i)
#pragma unroll
                for (int j = 0; j < 4; ++j)
                    S[i][j] = fmaf(ar[i], br[j], S[i][j]);
        }

        float pf[4][4];
#pragma unroll
        for (int i = 0; i < 4; ++i) {
            float mt = fmaxf(fmaxf(S[i][0], S[i][1]), fmaxf(S[i][2], S[i][3]));
#pragma unroll
            for (int msk = 1; msk < 16; msk <<= 1)
                mt = fmaxf(mt, __shfl_xor(mt, msk, 16));
            float mn = fmaxf(mrow[i], mt);
            float al = __expf(mrow[i] - mn);
            mrow[i] = mn;
            float rs = 0.f;
#pragma unroll
            for (int j = 0; j < 4; ++j) {
                float pv = __expf(S[i][j] - mn);
                pf[i][j] = pv;
                rs += pv;
            }
#pragma unroll
            for (int msk = 1; msk < 16; msk <<= 1)
                rs += __shfl_xor(rs, msk, 16);
            lrow[i] = lrow[i] * al + rs;
#pragma unroll
            for (int j = 0; j < 4; ++j) O[i][j] *= al;
        }

        __syncthreads();                       // done reading K
        // V tile -> LDS transposed w/ XOR-rotate (2-way, conflict-free)
#pragma unroll
        for (int ch = 0; ch < 4; ++ch) {
            int id = tid + ch * 256;
            int d = id >> 4, sc4 = (id & 15) * 4;
            float4 vv = *(const float4*)&vT[(bc + d) * 2048 + s0 + sc4];
            int cc = (d + sc4) & 63;
            KV[(sc4 + 0) * 64 + cc] = vv.x;
            KV[(sc4 + 1) * 64 + cc] = vv.y;
            KV[(sc4 + 2) * 64 + cc] = vv.z;
            KV[(sc4 + 3) * 64 + cc] = vv.w;
        }
#pragma unroll
        for (int i = 0; i < 4; ++i)
            *(float4*)&Ps[(ty4 + i) * 64 + tx4] =
                make_float4(pf[i][0], pf[i][1], pf[i][2], pf[i][3]);
        __syncthreads();

        // PV: O[t][d] += P[t][s] * V[s][d], s-chunks of 4; 8 b128 reads / 64 fma
#pragma unroll 4
        for (int sc = 0; sc < 16; ++sc) {
            int cp = (tx4 + sc * 4) & 63;       // un-rotated column base
            float4 vr[4], pr[4];
#pragma unroll
            for (int j = 0; j < 4; ++j)
                vr[j] = *(const float4*)&KV[(sc * 4 + j) * 64 + cp];
#pragma unroll
            for (int i = 0; i < 4; ++i)
                pr[i] = *(const float4*)&Ps[(ty4 + i) * 64 + sc * 4];
#pragma unroll
            for (int i = 0; i < 4; ++i) {
                const float* pp = (const float*)&pr[i];
#pragma unroll
                for (int j = 0; j < 4; ++j) {
                    const float* vp = (const float*)&vr[j];
                    float pij = pp[j];
                    O[i][0] = fmaf(pij, vp[0], O[i][0]);
                    O[i][1] = fmaf(pij, vp[1], O[i][1]);
                    O[i][2] = fmaf(pij, vp[2], O[i][2]);
                    O[i][3] = fmaf(pij, vp[3], O[i][3]);
                }
            }
        }
    }

    const int b = bh >> 4, h = bh & 15;
#pragma unroll
    for (int i = 0; i < 4; ++i) {
        float inv = 1.0f / lrow[i];
        float4 w = make_float4(O[i][0] * inv, O[i][1] * inv,
                               O[i][2] * inv, O[i][3] * inv);
        size_t row = (size_t)b * 2048 + t0 + ty4 + i;
        *(float4*)&att[row * 1024 + h * 64 + tx4] = w;
    }
}

// ------------------------------------------------------------- output GEMM (f32)
// out[m][n] = att[m][k] wo[k][n] + bo. 128x128 tile, 8x8 micro.
__global__ __launch_bounds__(256) void k_out_gemm(
    const float* __restrict__ att, const float* __restrict__ wo,
    const float* __restrict__ bo, float* __restrict__ out)
{
    __shared__ __align__(16) float As[16][128];   // As[k][m]
    __shared__ __align__(16) float Bs[16][128];   // Bs[k][n]
    const int tid = threadIdx.x;
    const int m0 = blockIdx.x * 128, n0 = blockIdx.y * 128;
    const int am = tid >> 1, ak = (tid & 1) * 8;
    const int bkr = tid >> 4, bn = (tid & 15) * 8;
    const int tx = tid & 15, ty = tid >> 4;           // micro: ty->m, tx->n

    const float* ax = &att[(size_t)(m0 + am) * 1024 + ak];
    const float* bw = &wo[(size_t)bkr * 1024 + n0 + bn];
    float4 pa0 = *(const float4*)ax, pa1 = *(const float4*)(ax + 4);
    float4 pb0 = *(const float4*)bw, pb1 = *(const float4*)(bw + 4);

    float acc[8][8] = {};
    for (int k0 = 0; k0 < 1024; k0 += 16) {
        __syncthreads();
        As[ak + 0][am] = pa0.x; As[ak + 1][am] = pa0.y;
        As[ak + 2][am] = pa0.z; As[ak + 3][am] = pa0.w;
        As[ak + 4][am] = pa1.x; As[ak + 5][am] = pa1.y;
        As[ak + 6][am] = pa1.z; As[ak + 7][am] = pa1.w;
        *(float4*)&Bs[bkr][bn] = pb0;
        *(float4*)&Bs[bkr][bn + 4] = pb1;
        __syncthreads();
        if (k0 < 1008) {
            const float* ax2 = &att[(size_t)(m0 + am) * 1024 + k0 + 16 + ak];
            pa0 = *(const float4*)ax2; pa1 = *(const float4*)(ax2 + 4);
            const float* bw2 = &wo[(size_t)(k0 + 16 + bkr) * 1024 + n0 + bn];
            pb0 = *(const float4*)bw2; pb1 = *(const float4*)(bw2 + 4);
        }
#pragma unroll
        for (int kk = 0; kk < 16; ++kk) {
            float4 a0 = *(const float4*)&As[kk][ty * 8];
            float4 a1 = *(const float4*)&As[kk][ty * 8 + 4];
            float4 b0 = *(const float4*)&Bs[kk][tx * 8];
            float4 b1 = *(const float4*)&Bs[kk][tx * 8 + 4];
            float ar[8] = {a0.x, a0.y, a0.z, a0.w, a1.x, a1.y, a1.z, a1.w};
            float br[8] = {b0.x, b0.y, b0.z, b0.w, b1.x, b1.y, b1.z, b1.w};
#pragma unroll
            for (int i = 0; i < 8; ++i)
#pragma unroll
                for (int j = 0; j < 8; ++j)
                    acc[i][j] = fmaf(ar[i], br[j], acc[i][j]);
        }
    }
    float4 bb0 = *(const float4*)&bo[n0 + tx * 8];
    float4 bb1 = *(const float4*)&bo[n0 + tx * 8 + 4];
#pragma unroll
    for (int i = 0; i < 8; ++i) {
        float4 o0 = make_float4(acc[i][0] + bb0.x, acc[i][1] + bb0.y,
                                acc[i][2] + bb0.z, acc[i][3] + bb0.w);
        float4 o1 = make_float4(acc[i][4] + bb1.x, acc[i][5] + bb1.y,
                                acc[i][6] + bb1.z, acc[i][7] + bb1.w);
        float* op = &out[(size_t)(m0 + ty * 8 + i) * 1024 + n0 + tx * 8];
        *(float4*)op = o0;
        *(float4*)(op + 4) = o1;
    }
}

// ------------------------------------------------------------- energy renorm
__global__ __launch_bounds__(256) void k_norm(
    const float* __restrict__ x, float* __restrict__ out,
    const float* __restrict__ en)
{
    const int row = blockIdx.x;
    const int tid = threadIdx.x;
    const float* xr = x + (size_t)row * 1024;
    float* orow = out + (size_t)row * 1024;
    float4 xv = *(const float4*)&xr[tid * 4];
    float4 ov = *(const float4*)&orow[tid * 4];
    float ssx = xv.x * xv.x + xv.y * xv.y + xv.z * xv.z + xv.w * xv.w;
    float sso = ov.x * ov.x + ov.y * ov.y + ov.z * ov.z + ov.w * ov.w;
#pragma unroll
    for (int m = 1; m <= 32; m <<= 1) {
        ssx += __shfl_xor(ssx, m, 64);
        sso += __shfl_xor(sso, m, 64);
    }
    __shared__ float rx[4], ro[4];
    const int wid = tid >> 6;
    if ((tid & 63) == 0) { rx[wid] = ssx; ro[wid] = sso; }
    __syncthreads();
    float tsx = rx[0] + rx[1] + rx[2] + rx[3];
    float tso = ro[0] + ro[1] + ro[2] + ro[3];
    float scale = sqrtf(tsx) / (sqrtf(tso) + 1e-8f) * en[0];
    ov.x *= scale; ov.y *= scale; ov.z *= scale; ov.w *= scale;
    *(float4*)&orow[tid * 4] = ov;
}

// ------------------------------------------------------------- launch
extern "C" void kernel_launch(void* const* d_in, const int* in_sizes, int n_in,
                              void* d_out, int out_size, void* d_ws, size_t ws_size,
                              hipStream_t stream)
{
    const float* x     = (const float*)d_in[0];
    const float* fd    = (const float*)d_in[1];
    const float* wq    = (const float*)d_in[2];
    const float* bq    = (const float*)d_in[3];
    const float* wk    = (const float*)d_in[4];
    const float* bk    = (const float*)d_in[5];
    const float* wv    = (const float*)d_in[6];
    const float* bv    = (const float*)d_in[7];
    const float* wo    = (const float*)d_in[8];
    const float* bo    = (const float*)d_in[9];
    const float* alpha = (const float*)d_in[10];
    const float* fas   = (const float*)d_in[11];
    const float* en    = (const float*)d_in[12];
    float* out = (float*)d_out;
    float* ws  = (float*)d_ws;

    float* qT  = ws;
    float* kT  = ws + (size_t)1 * 4194304;
    float* vT  = ws + (size_t)2 * 4194304;
    float* qiT = ws + (size_t)3 * 4194304;
    float* kiT = ws + (size_t)4 * 4194304;
    float* att = ws + (size_t)5 * 4194304;
    float2* tw   = (float2*)(ws + (size_t)6 * 4194304);
    float2* filt = (float2*)(ws + (size_t)6 * 4194304 + 2048);

    k_init_tables<<<8, 256, 0, stream>>>(tw, filt, fd, alpha, fas);
    k_qkv_gemm<<<dim3(32, 8, 3), 256, 0, stream>>>(x, wq, bq, wk, bk, wv, bv, qT, kT, vT);
    k_fft_filter<<<6144, 256, 0, stream>>>(qT, kT, vT, qiT, kiT, tw, filt);
    k_flash<<<1024, 256, 0, stream>>>(qT, qiT, kT, kiT, vT, att);
    k_out_gemm<<<dim3(32, 8), 256, 0, stream>>>(att, wo, bo, out);
    k_norm<<<4096, 256, 0, stream>>>(x, out, en);
}

// Round 3
// 851.383 us; speedup vs baseline: 2.4875x; 1.7765x over previous
//
#include <hip/hip_runtime.h>
#include <math.h>

// SpectralAttention gfx950 — round 3: MFMA f16-split flash attention.
// B=2, T=2048, C=1024, H=16, HD=64.
//
// Precision scheme: every spectral value v (fp32) is stored as a packed
// uint32: lo16 bits = fp16(v) ["hi" part], hi16 bits = fp16((v-hi)*2048)
// ["lo" part, pre-scaled by 2^11]. v ≈ hi + lo/2048 to ~2^-22 relative.
// S-logits: S = Qhi*Khi + (Qhi*Klo + Qlo*Khi)/2048  (3 MFMA terms, fp32-equiv)
// PV:       O = P*Vhi + (P*Vlo)/2048                (2 MFMA terms)
//
// ws layout (16MB planes, packed-u32 after FFT):
//   qpk  [0,  4M) : packed split of 0.125*Re(qf)   [b][c][t]
//   kpk  [4M, 8M) : packed split of Re(kf)
//   vpk  [8M, 12M): packed split of Re(vf)
//   qipk [12M,16M): packed split of 0.125*Im(qf)
//   kipk [16M,20M): packed split of -Im(kf)
//   att  [20M,24M): attended fp32 [b*t][c]
//   tables at 24M
// total 96 MB + 16 KB (unchanged from round 2)

typedef _Float16 half8 __attribute__((ext_vector_type(8)));
typedef float f32x4 __attribute__((ext_vector_type(4)));
#define MFMA16 __builtin_amdgcn_mfma_f32_16x16x32_f16

__device__ inline unsigned pack_split(float v) {
    _Float16 h = (_Float16)v;
    float r = (v - (float)h) * 2048.0f;
    _Float16 l = (_Float16)r;
    union { _Float16 f; unsigned short u; } a, b;
    a.f = h; b.f = l;
    return (unsigned)a.u | ((unsigned)b.u << 16);
}
__device__ inline _Float16 lo16(unsigned u) {
    union { unsigned short s; _Float16 f; } x; x.s = (unsigned short)(u & 0xffffu); return x.f;
}
__device__ inline _Float16 hi16(unsigned u) {
    union { unsigned short s; _Float16 f; } x; x.s = (unsigned short)(u >> 16); return x.f;
}

// ---------------------------------------------------------------- init tables
__global__ __launch_bounds__(256) void k_init_tables(
    float2* __restrict__ tw, float2* __restrict__ filt,
    const float* __restrict__ fd, const float* __restrict__ alpha,
    const float* __restrict__ fas)
{
    int i = blockIdx.x * 256 + threadIdx.x;   // grid 8*256 = 2048
    double aa = (double)alpha[0] + (double)fas[0] * ((double)fd[0] - 1.5);
    if (i < 1024) {
        double ang = -2.0 * 3.14159265358979323846 * (double)i / 2048.0;
        double s, c;
        sincos(ang, &s, &c);
        tw[i] = make_float2((float)c, (float)s);
    }
    if (i < 2048) {
        double fr = (i < 1024) ? (double)i / 2048.0 : ((double)i - 2048.0) / 2048.0;
        double ph = aa * atan(log(fabs(fr) + 1e-10));
        double s, c;
        sincos(ph, &s, &c);
        filt[i] = make_float2((float)c, (float)s);
    }
}

// ------------------------------------------------------------- QKV GEMM (f32)
// C^T = W^T X^T: out[c][t] fp32, 128x128 tile, 8x8 micro/lane.
__global__ __launch_bounds__(256) void k_qkv_gemm(
    const float* __restrict__ x,
    const float* __restrict__ wq, const float* __restrict__ bq,
    const float* __restrict__ wk, const float* __restrict__ bk,
    const float* __restrict__ wv, const float* __restrict__ bv,
    float* __restrict__ qT, float* __restrict__ kT, float* __restrict__ vT)
{
    __shared__ __align__(16) float As[16][128];
    __shared__ __align__(16) float Bs[16][128];
    const int tid = threadIdx.x;
    const int mat = blockIdx.z;
    const float* W    = (mat == 0) ? wq : (mat == 1) ? wk : wv;
    const float* bias = (mat == 0) ? bq : (mat == 1) ? bk : bv;
    float* outp       = (mat == 0) ? qT : (mat == 1) ? kT : vT;
    const int m0 = blockIdx.x * 128, n0 = blockIdx.y * 128;
    const int am = tid >> 1, ak = (tid & 1) * 8;
    const int bkr = tid >> 4, bn = (tid & 15) * 8;
    const int tx = tid & 15, ty = tid >> 4;

    const float* ax = &x[(size_t)(m0 + am) * 1024 + ak];
    const float* bw = &W[(size_t)bkr * 1024 + n0 + bn];
    float4 pa0 = *(const float4*)ax, pa1 = *(const float4*)(ax + 4);
    float4 pb0 = *(const float4*)bw, pb1 = *(const float4*)(bw + 4);

    float acc[8][8] = {};
    for (int k0 = 0; k0 < 1024; k0 += 16) {
        __syncthreads();
        As[ak + 0][am] = pa0.x; As[ak + 1][am] = pa0.y;
        As[ak + 2][am] = pa0.z; As[ak + 3][am] = pa0.w;
        As[ak + 4][am] = pa1.x; As[ak + 5][am] = pa1.y;
        As[ak + 6][am] = pa1.z; As[ak + 7][am] = pa1.w;
        *(float4*)&Bs[bkr][bn] = pb0;
        *(float4*)&Bs[bkr][bn + 4] = pb1;
        __syncthreads();
        if (k0 < 1008) {
            const float* ax2 = &x[(size_t)(m0 + am) * 1024 + k0 + 16 + ak];
            pa0 = *(const float4*)ax2; pa1 = *(const float4*)(ax2 + 4);
            const float* bw2 = &W[(size_t)(k0 + 16 + bkr) * 1024 + n0 + bn];
            pb0 = *(const float4*)bw2; pb1 = *(const float4*)(bw2 + 4);
        }
#pragma unroll
        for (int kk = 0; kk < 16; ++kk) {
            float4 w0 = *(const float4*)&Bs[kk][ty * 8];
            float4 w1 = *(const float4*)&Bs[kk][ty * 8 + 4];
            float4 x0 = *(const float4*)&As[kk][tx * 8];
            float4 x1 = *(const float4*)&As[kk][tx * 8 + 4];
            float wr[8] = {w0.x, w0.y, w0.z, w0.w, w1.x, w1.y, w1.z, w1.w};
            float xr[8] = {x0.x, x0.y, x0.z, x0.w, x1.x, x1.y, x1.z, x1.w};
#pragma unroll
            for (int i = 0; i < 8; ++i)
#pragma unroll
                for (int j = 0; j < 8; ++j)
                    acc[i][j] = fmaf(wr[i], xr[j], acc[i][j]);
        }
    }
    const int b_ = m0 >> 11;
    const int tbase = (m0 & 2047) + tx * 8;
#pragma unroll
    for (int i = 0; i < 8; ++i) {
        int n = n0 + ty * 8 + i;
        float bv_ = bias[n];
        float4 o0 = make_float4(acc[i][0] + bv_, acc[i][1] + bv_,
                                acc[i][2] + bv_, acc[i][3] + bv_);
        float4 o1 = make_float4(acc[i][4] + bv_, acc[i][5] + bv_,
                                acc[i][6] + bv_, acc[i][7] + bv_);
        float* op = &outp[((size_t)(b_ * 1024 + n)) * 2048 + tbase];
        *(float4*)op = o0;
        *(float4*)(op + 4) = o1;
    }
}

// ------------------------------------------------------------- FFT + filter
// In-place per-sequence: read fp32, write packed fp16-split uint32.
__global__ __launch_bounds__(256) void k_fft_filter(
    float* __restrict__ qT, float* __restrict__ kT, float* __restrict__ vT,
    float* __restrict__ qiT, float* __restrict__ kiT,
    const float2* __restrict__ tw, const float2* __restrict__ filt)
{
    __shared__ float2 sf[2048];
    const int bid = blockIdx.x;          // 0..6143
    const int mat = bid >> 11;
    const int seq = bid & 2047;
    float* base = (mat == 0) ? qT : (mat == 1) ? kT : vT;
    float* src = base + (size_t)seq * 2048;
    const int tid = threadIdx.x;

    for (int i = tid; i < 2048; i += 256) {
        int j = (int)(__brev((unsigned)i) >> 21);
        sf[j] = make_float2(src[i], 0.f);
    }
    __syncthreads();
    for (int st = 1; st <= 11; ++st) {
        const int half = 1 << (st - 1);
        const int shift = 11 - st;
        for (int u = tid; u < 1024; u += 256) {
            int pos = u & (half - 1);
            int bi = 2 * u - pos;
            float2 w = tw[pos << shift];
            float2 a = sf[bi], b = sf[bi + half];
            float tr = w.x * b.x - w.y * b.y;
            float ti = w.x * b.y + w.y * b.x;
            sf[bi]        = make_float2(a.x + tr, a.y + ti);
            sf[bi + half] = make_float2(a.x - tr, a.y - ti);
        }
        __syncthreads();
    }
    unsigned* dst_re = (unsigned*)src;
    unsigned* dst_im = (mat == 0) ? (unsigned*)(qiT + (size_t)seq * 2048)
                                  : (unsigned*)(kiT + (size_t)seq * 2048);
    for (int i = tid; i < 2048; i += 256) {
        float2 z = sf[i];
        float2 f = filt[i];
        float re = z.x * f.x - z.y * f.y;
        float im = z.x * f.y + z.y * f.x;
        if (mat == 0) {
            dst_re[i] = pack_split(0.125f * re);        // fold 1/sqrt(64)
            dst_im[i] = pack_split(0.125f * im);
        } else if (mat == 1) {
            dst_re[i] = pack_split(re);
            dst_im[i] = pack_split(-im);                 // fold minus sign
        } else {
            dst_re[i] = pack_split(re);
        }
    }
}

// ------------------------------------------------------------- flash (MFMA f16)
// 512 thr = 8 waves; block = (bh, t-tile 128); wave owns 16 t-rows; s-step 32.
// mfma_f32_16x16x32_f16 frags: A[m=lane&15][k=quad*8+j], B[n=lane&15][k=quad*8+j],
// C/D: col=lane&15, row=quad*4+reg.
__global__ __launch_bounds__(512) void k_flash(
    const unsigned* __restrict__ qpk, const unsigned* __restrict__ qipk,
    const unsigned* __restrict__ kpk, const unsigned* __restrict__ kipk,
    const unsigned* __restrict__ vpk, float* __restrict__ att)
{
    __shared__ __align__(16) _Float16 Kbuf[2][4][2][64][8];  // st,kc,sp  16KB
    __shared__ __align__(16) _Float16 Vbuf[4][2][64][8];     // nt,sp      8KB
    __shared__ __align__(16) _Float16 Pbuf[8][16][32];       // w,t,s      8KB

    const int tid = threadIdx.x;
    const int w = tid >> 6, lane = tid & 63;
    const int quad = lane >> 4, l15 = lane & 15;
    const int bh = blockIdx.x >> 4, tb = blockIdx.x & 15;
    const size_t bc = (size_t)bh * 64;
    const int tw0 = tb * 128 + w * 16;

    // Q A-frags in registers: [kc 0..3] hi+lo, loaded once, reused 64 iters.
    half8 aqh[4], aql[4];
#pragma unroll
    for (int kc = 0; kc < 4; ++kc) {
#pragma unroll
        for (int j = 0; j < 8; ++j) {
            int d = kc * 32 + quad * 8 + j;
            int t = tw0 + l15;
            unsigned u = (d < 64) ? qpk[(bc + d) * 2048 + t]
                                  : qipk[(bc + d - 64) * 2048 + t];
            aqh[kc][j] = lo16(u);
            aql[kc][j] = hi16(u);
        }
    }

    f32x4 O1[4], O2[4];
    const f32x4 zero4 = {0.f, 0.f, 0.f, 0.f};
#pragma unroll
    for (int nt = 0; nt < 4; ++nt) { O1[nt] = zero4; O2[nt] = zero4; }
    float m_[4] = {-3e38f, -3e38f, -3e38f, -3e38f};
    float l_[4] = {0.f, 0.f, 0.f, 0.f};

    // staging index precompute
    const int sK = tid & 31, dcK = tid >> 5;          // K: 32s x 16 d-chunks
    const int stK = sK >> 4, kcK = dcK >> 2, qK = dcK & 3;
    const int laneK = (sK & 15) + qK * 16;
    const int sV = tid & 31, dcV = tid >> 5;          // V: 32s x 8 d-chunks (tid<256)

    for (int s0 = 0; s0 < 2048; s0 += 32) {
        __syncthreads();                               // prev-iter reads done
        // --- stage K (all 512 threads): 8 u32 loads -> 2 b128 LDS writes
        {
            half8 kh, kl;
#pragma unroll
            for (int j = 0; j < 8; ++j) {
                int d = dcK * 8 + j;
                unsigned u = (d < 64) ? kpk[(bc + d) * 2048 + s0 + sK]
                                      : kipk[(bc + d - 64) * 2048 + s0 + sK];
                kh[j] = lo16(u);
                kl[j] = hi16(u);
            }
            *(half8*)&Kbuf[stK][kcK][0][laneK][0] = kh;
            *(half8*)&Kbuf[stK][kcK][1][laneK][0] = kl;
        }
        // --- stage V (threads 0..255): scatter fp16 pairs into frag layout
        if (tid < 256) {
#pragma unroll
            for (int j = 0; j < 8; ++j) {
                int d = dcV * 8 + j;
                unsigned u = vpk[(bc + d) * 2048 + s0 + sV];
                int nt = d >> 4, ln = (d & 15) + (sV >> 3) * 16;
                Vbuf[nt][0][ln][sV & 7] = lo16(u);
                Vbuf[nt][1][ln][sV & 7] = hi16(u);
            }
        }
        __syncthreads();

        // --- S = Q.K^T via 3-term split MFMA
        f32x4 S1[2], S2[2];
#pragma unroll
        for (int st = 0; st < 2; ++st) { S1[st] = zero4; S2[st] = zero4; }
#pragma unroll
        for (int st = 0; st < 2; ++st) {
#pragma unroll
            for (int kc = 0; kc < 4; ++kc) {
                half8 bhf = *(half8*)&Kbuf[st][kc][0][lane][0];
                half8 blf = *(half8*)&Kbuf[st][kc][1][lane][0];
                S1[st] = MFMA16(aqh[kc], bhf, S1[st], 0, 0, 0);
                S2[st] = MFMA16(aqh[kc], blf, S2[st], 0, 0, 0);
                S2[st] = MFMA16(aql[kc], bhf, S2[st], 0, 0, 0);
            }
        }

        // --- online softmax (rows: t = quad*4 + r; cols: l15 + st*16)
#pragma unroll
        for (int r = 0; r < 4; ++r) {
            float v0 = S1[0][r] + S2[0][r] * (1.f / 2048.f);
            float v1 = S1[1][r] + S2[1][r] * (1.f / 2048.f);
            float mt = fmaxf(v0, v1);
#pragma unroll
            for (int msk = 1; msk < 16; msk <<= 1)
                mt = fmaxf(mt, __shfl_xor(mt, msk, 16));
            float mn = fmaxf(m_[r], mt);
            float al = __expf(m_[r] - mn);
            m_[r] = mn;
            float p0 = __expf(v0 - mn);
            float p1 = __expf(v1 - mn);
            float rs = p0 + p1;
#pragma unroll
            for (int msk = 1; msk < 16; msk <<= 1)
                rs += __shfl_xor(rs, msk, 16);
            l_[r] = l_[r] * al + rs;
#pragma unroll
            for (int nt = 0; nt < 4; ++nt) { O1[nt][r] *= al; O2[nt][r] *= al; }
            int t = quad * 4 + r;
            Pbuf[w][t][l15]      = (_Float16)p0;
            Pbuf[w][t][l15 + 16] = (_Float16)p1;
        }
        // wave-private Pbuf: no barrier needed (compiler orders LDS deps)

        // --- PV accumulate
        half8 ap = *(half8*)&Pbuf[w][l15][quad * 8];
#pragma unroll
        for (int nt = 0; nt < 4; ++nt) {
            half8 vh = *(half8*)&Vbuf[nt][0][lane][0];
            half8 vl = *(half8*)&Vbuf[nt][1][lane][0];
            O1[nt] = MFMA16(ap, vh, O1[nt], 0, 0, 0);
            O2[nt] = MFMA16(ap, vl, O2[nt], 0, 0, 0);
        }
    }

    // epilogue: O/l -> att[b*2048+t][h*64+d]
    const int b = bh >> 4, h = bh & 15;
#pragma unroll
    for (int r = 0; r < 4; ++r) {
        float inv = 1.0f / l_[r];
        int t = tw0 + quad * 4 + r;
        size_t row = (size_t)b * 2048 + t;
#pragma unroll
        for (int nt = 0; nt < 4; ++nt) {
            float val = (O1[nt][r] + O2[nt][r] * (1.f / 2048.f)) * inv;
            att[row * 1024 + h * 64 + nt * 16 + l15] = val;
        }
    }
}

// ------------------------------------------------------------- output GEMM (f32)
__global__ __launch_bounds__(256) void k_out_gemm(
    const float* __restrict__ att, const float* __restrict__ wo,
    const float* __restrict__ bo, float* __restrict__ out)
{
    __shared__ __align__(16) float As[16][128];
    __shared__ __align__(16) float Bs[16][128];
    const int tid = threadIdx.x;
    const int m0 = blockIdx.x * 128, n0 = blockIdx.y * 128;
    const int am = tid >> 1, ak = (tid & 1) * 8;
    const int bkr = tid >> 4, bn = (tid & 15) * 8;
    const int tx = tid & 15, ty = tid >> 4;

    const float* ax = &att[(size_t)(m0 + am) * 1024 + ak];
    const float* bw = &wo[(size_t)bkr * 1024 + n0 + bn];
    float4 pa0 = *(const float4*)ax, pa1 = *(const float4*)(ax + 4);
    float4 pb0 = *(const float4*)bw, pb1 = *(const float4*)(bw + 4);

    float acc[8][8] = {};
    for (int k0 = 0; k0 < 1024; k0 += 16) {
        __syncthreads();
        As[ak + 0][am] = pa0.x; As[ak + 1][am] = pa0.y;
        As[ak + 2][am] = pa0.z; As[ak + 3][am] = pa0.w;
        As[ak + 4][am] = pa1.x; As[ak + 5][am] = pa1.y;
        As[ak + 6][am] = pa1.z; As[ak + 7][am] = pa1.w;
        *(float4*)&Bs[bkr][bn] = pb0;
        *(float4*)&Bs[bkr][bn + 4] = pb1;
        __syncthreads();
        if (k0 < 1008) {
            const float* ax2 = &att[(size_t)(m0 + am) * 1024 + k0 + 16 + ak];
            pa0 = *(const float4*)ax2; pa1 = *(const float4*)(ax2 + 4);
            const float* bw2 = &wo[(size_t)(k0 + 16 + bkr) * 1024 + n0 + bn];
            pb0 = *(const float4*)bw2; pb1 = *(const float4*)(bw2 + 4);
        }
#pragma unroll
        for (int kk = 0; kk < 16; ++kk) {
            float4 a0 = *(const float4*)&As[kk][ty * 8];
            float4 a1 = *(const float4*)&As[kk][ty * 8 + 4];
            float4 b0 = *(const float4*)&Bs[kk][tx * 8];
            float4 b1 = *(const float4*)&Bs[kk][tx * 8 + 4];
            float ar[8] = {a0.x, a0.y, a0.z, a0.w, a1.x, a1.y, a1.z, a1.w};
            float br[8] = {b0.x, b0.y, b0.z, b0.w, b1.x, b1.y, b1.z, b1.w};
#pragma unroll
            for (int i = 0; i < 8; ++i)
#pragma unroll
                for (int j = 0; j < 8; ++j)
                    acc[i][j] = fmaf(ar[i], br[j], acc[i][j]);
        }
    }
    float4 bb0 = *(const float4*)&bo[n0 + tx * 8];
    float4 bb1 = *(const float4*)&bo[n0 + tx * 8 + 4];
#pragma unroll
    for (int i = 0; i < 8; ++i) {
        float4 o0 = make_float4(acc[i][0] + bb0.x, acc[i][1] + bb0.y,
                                acc[i][2] + bb0.z, acc[i][3] + bb0.w);
        float4 o1 = make_float4(acc[i][4] + bb1.x, acc[i][5] + bb1.y,
                                acc[i][6] + bb1.z, acc[i][7] + bb1.w);
        float* op = &out[(size_t)(m0 + ty * 8 + i) * 1024 + n0 + tx * 8];
        *(float4*)op = o0;
        *(float4*)(op + 4) = o1;
    }
}

// ------------------------------------------------------------- energy renorm
__global__ __launch_bounds__(256) void k_norm(
    const float* __restrict__ x, float* __restrict__ out,
    const float* __restrict__ en)
{
    const int row = blockIdx.x;
    const int tid = threadIdx.x;
    const float* xr = x + (size_t)row * 1024;
    float* orow = out + (size_t)row * 1024;
    float4 xv = *(const float4*)&xr[tid * 4];
    float4 ov = *(const float4*)&orow[tid * 4];
    float ssx = xv.x * xv.x + xv.y * xv.y + xv.z * xv.z + xv.w * xv.w;
    float sso = ov.x * ov.x + ov.y * ov.y + ov.z * ov.z + ov.w * ov.w;
#pragma unroll
    for (int m = 1; m <= 32; m <<= 1) {
        ssx += __shfl_xor(ssx, m, 64);
        sso += __shfl_xor(sso, m, 64);
    }
    __shared__ float rx[4], ro[4];
    const int wid = tid >> 6;
    if ((tid & 63) == 0) { rx[wid] = ssx; ro[wid] = sso; }
    __syncthreads();
    float tsx = rx[0] + rx[1] + rx[2] + rx[3];
    float tso = ro[0] + ro[1] + ro[2] + ro[3];
    float scale = sqrtf(tsx) / (sqrtf(tso) + 1e-8f) * en[0];
    ov.x *= scale; ov.y *= scale; ov.z *= scale; ov.w *= scale;
    *(float4*)&orow[tid * 4] = ov;
}

// ------------------------------------------------------------- launch
extern "C" void kernel_launch(void* const* d_in, const int* in_sizes, int n_in,
                              void* d_out, int out_size, void* d_ws, size_t ws_size,
                              hipStream_t stream)
{
    const float* x     = (const float*)d_in[0];
    const float* fd    = (const float*)d_in[1];
    const float* wq    = (const float*)d_in[2];
    const float* bq    = (const float*)d_in[3];
    const float* wk    = (const float*)d_in[4];
    const float* bk    = (const float*)d_in[5];
    const float* wv    = (const float*)d_in[6];
    const float* bv    = (const float*)d_in[7];
    const float* wo    = (const float*)d_in[8];
    const float* bo    = (const float*)d_in[9];
    const float* alpha = (const float*)d_in[10];
    const float* fas   = (const float*)d_in[11];
    const float* en    = (const float*)d_in[12];
    float* out = (float*)d_out;
    float* ws  = (float*)d_ws;

    float* qT  = ws;
    float* kT  = ws + (size_t)1 * 4194304;
    float* vT  = ws + (size_t)2 * 4194304;
    float* qiT = ws + (size_t)3 * 4194304;
    float* kiT = ws + (size_t)4 * 4194304;
    float* att = ws + (size_t)5 * 4194304;
    float2* tw   = (float2*)(ws + (size_t)6 * 4194304);
    float2* filt = (float2*)(ws + (size_t)6 * 4194304 + 2048);

    k_init_tables<<<8, 256, 0, stream>>>(tw, filt, fd, alpha, fas);
    k_qkv_gemm<<<dim3(32, 8, 3), 256, 0, stream>>>(x, wq, bq, wk, bk, wv, bv, qT, kT, vT);
    k_fft_filter<<<6144, 256, 0, stream>>>(qT, kT, vT, qiT, kiT, tw, filt);
    k_flash<<<512, 512, 0, stream>>>((const unsigned*)qT, (const unsigned*)qiT,
                                     (const unsigned*)kT, (const unsigned*)kiT,
                                     (const unsigned*)vT, att);
    k_out_gemm<<<dim3(32, 8), 256, 0, stream>>>(att, wo, bo, out);
    k_norm<<<4096, 256, 0, stream>>>(x, out, en);
}

// Round 4
// 591.409 us; speedup vs baseline: 3.5810x; 1.4396x over previous
//
#include <hip/hip_runtime.h>
#include <math.h>

// SpectralAttention gfx950 — round 4: split-fp16 MFMA for ALL GEMMs.
// B=2, T=2048, C=1024, H=16, HD=64.
//
// Packed split format (u32): lo16 = fp16(v) ["hi" part], hi16 = fp16((v-hi)*2048).
// v = hi + lo/2048 to ~2^-22 rel.  3-term MFMA: D = Ah*Bh + (Ah*Bl + Al*Bh)/2048.
//
// ws layout (floats) with region reuse (stream-ordered lifetimes):
//   [0,  4M)  qT: q fp32 -> qpk packed (fft) -> Wo-pk (prep_wo, after flash)
//   [4M, 8M)  kT: k fp32 -> kpk
//   [8M, 12M) vT: v fp32 -> vpk
//   [12M,16M) Wq/Wk/Wv-pk (prep) -> qipk (fft overwrites; Wpk consumed by qkv GEMM)
//   [16M,20M) kipk
//   [20M,24M) xpk (prep) -> attpk (flash overwrites; xpk consumed by qkv GEMM)
//   24M: tables (float2[1024] tw + float2[2048] filt)
// total 96 MB + 16 KB

typedef _Float16 half8 __attribute__((ext_vector_type(8)));
typedef float f32x4 __attribute__((ext_vector_type(4)));
#define MFMA16 __builtin_amdgcn_mfma_f32_16x16x32_f16

__device__ inline unsigned pack_split(float v) {
    _Float16 h = (_Float16)v;
    float r = (v - (float)h) * 2048.0f;
    _Float16 l = (_Float16)r;
    union { _Float16 f; unsigned short u; } a, b;
    a.f = h; b.f = l;
    return (unsigned)a.u | ((unsigned)b.u << 16);
}
__device__ inline _Float16 lo16(unsigned u) {
    union { unsigned short s; _Float16 f; } x; x.s = (unsigned short)(u & 0xffffu); return x.f;
}
__device__ inline _Float16 hi16(unsigned u) {
    union { unsigned short s; _Float16 f; } x; x.s = (unsigned short)(u >> 16); return x.f;
}

// split a chunk of 8 packed u32 into hi-half8 / lo-half8 via byte-perms
__device__ inline void write_split(_Float16* dh, _Float16* dl, uint4 u0, uint4 u1) {
    uint4 lo, hi;
    lo.x = __builtin_amdgcn_perm(u0.y, u0.x, 0x05040100u);
    lo.y = __builtin_amdgcn_perm(u0.w, u0.z, 0x05040100u);
    lo.z = __builtin_amdgcn_perm(u1.y, u1.x, 0x05040100u);
    lo.w = __builtin_amdgcn_perm(u1.w, u1.z, 0x05040100u);
    hi.x = __builtin_amdgcn_perm(u0.y, u0.x, 0x07060302u);
    hi.y = __builtin_amdgcn_perm(u0.w, u0.z, 0x07060302u);
    hi.z = __builtin_amdgcn_perm(u1.y, u1.x, 0x07060302u);
    hi.w = __builtin_amdgcn_perm(u1.w, u1.z, 0x07060302u);
    *(uint4*)dh = lo;   // fp16 "hi" parts
    *(uint4*)dl = hi;   // fp16 "lo" parts (pre-scaled x2048)
}

// ---------------------------------------------------------------- init tables
__global__ __launch_bounds__(256) void k_init_tables(
    float2* __restrict__ tw, float2* __restrict__ filt,
    const float* __restrict__ fd, const float* __restrict__ alpha,
    const float* __restrict__ fas)
{
    int i = blockIdx.x * 256 + threadIdx.x;
    double aa = (double)alpha[0] + (double)fas[0] * ((double)fd[0] - 1.5);
    if (i < 1024) {
        double ang = -2.0 * 3.14159265358979323846 * (double)i / 2048.0;
        double s, c;
        sincos(ang, &s, &c);
        tw[i] = make_float2((float)c, (float)s);
    }
    if (i < 2048) {
        double fr = (i < 1024) ? (double)i / 2048.0 : ((double)i - 2048.0) / 2048.0;
        double ph = aa * atan(log(fabs(fr) + 1e-10));
        double s, c;
        sincos(ph, &s, &c);
        filt[i] = make_float2((float)c, (float)s);
    }
}

// ------------------------------------------------------- prep: W^T pack-split
// W [k][c] fp32 -> Wpk [c][k] packed u32.  grid (16,16).
__global__ __launch_bounds__(256) void k_prep_w(
    const float* __restrict__ W, unsigned* __restrict__ Wpk)
{
    __shared__ float tile[64][65];
    const int kb = blockIdx.x * 64, cb = blockIdx.y * 64;
    const int t = threadIdx.x, r = t >> 4, c4 = (t & 15) * 4;
#pragma unroll
    for (int i = 0; i < 4; ++i) {
        int row = r + 16 * i;
        float4 v = *(const float4*)&W[(size_t)(kb + row) * 1024 + cb + c4];
        tile[row][c4 + 0] = v.x; tile[row][c4 + 1] = v.y;
        tile[row][c4 + 2] = v.z; tile[row][c4 + 3] = v.w;
    }
    __syncthreads();
#pragma unroll
    for (int i = 0; i < 4; ++i) {
        int crow = r + 16 * i;
        uint4 o;
        o.x = pack_split(tile[c4 + 0][crow]);
        o.y = pack_split(tile[c4 + 1][crow]);
        o.z = pack_split(tile[c4 + 2][crow]);
        o.w = pack_split(tile[c4 + 3][crow]);
        *(uint4*)&Wpk[(size_t)(cb + crow) * 1024 + kb + c4] = o;
    }
}

// ------------------------------------------------------- prep: x pack-split
__global__ __launch_bounds__(256) void k_prep_x(
    const float* __restrict__ x, unsigned* __restrict__ xpk)
{
    const int base = blockIdx.x * 4096 + threadIdx.x * 4;
#pragma unroll
    for (int i = 0; i < 4; ++i) {
        int idx = base + i * 1024;
        float4 v = *(const float4*)&x[idx];
        uint4 o;
        o.x = pack_split(v.x); o.y = pack_split(v.y);
        o.z = pack_split(v.z); o.w = pack_split(v.w);
        *(uint4*)&xpk[idx] = o;
    }
}

// --------------------------------------------------- QKV GEMM (MFMA f16-split)
// out^T[c][t] = W^T X^T: M=c_out(1024), N=b.t(4096), K=1024.
// A = Wpk[c][k], B = xpk[t][k]. 128x128 tile, 4 waves x (4x4 of 16x16x32).
__global__ __launch_bounds__(256) void k_gemm_qkv(
    const unsigned* __restrict__ xpk, const unsigned* __restrict__ wpk,
    const float* __restrict__ bq, const float* __restrict__ bk,
    const float* __restrict__ bv,
    float* __restrict__ qT, float* __restrict__ kT, float* __restrict__ vT)
{
    __shared__ __align__(16) _Float16 Ab[8][2][64][8];   // 16 KB
    __shared__ __align__(16) _Float16 Bb[8][2][64][8];   // 16 KB
    const int tid = threadIdx.x;
    const int mat = blockIdx.z;
    const unsigned* Apk = wpk + (size_t)mat * 1048576;
    const float* bias = (mat == 0) ? bq : (mat == 1) ? bk : bv;
    float* outp       = (mat == 0) ? qT : (mat == 1) ? kT : vT;
    const int m0 = blockIdx.x * 128, n0 = blockIdx.y * 128;
    const int w = tid >> 6, lane = tid & 63, quad = lane >> 4, l15 = lane & 15;
    const int wm = (w & 1) * 4, wn = (w >> 1) * 4;

    // staging tasks: id = tid (rows rA, mt=rA>>4) and tid+256 (rows rA+64)
    const int chA = tid & 3, rA = tid >> 2;
    const int flA = (rA & 15) + 16 * chA, mtA = rA >> 4;
    const unsigned* gA0 = &Apk[(size_t)(m0 + rA) * 1024 + chA * 8];
    const unsigned* gA1 = gA0 + (size_t)64 * 1024;
    const unsigned* gB0 = &xpk[(size_t)(n0 + rA) * 1024 + chA * 8];
    const unsigned* gB1 = gB0 + (size_t)64 * 1024;

    uint4 pa0 = *(const uint4*)gA0, pa1 = *(const uint4*)(gA0 + 4);
    uint4 pa2 = *(const uint4*)gA1, pa3 = *(const uint4*)(gA1 + 4);
    uint4 pb0 = *(const uint4*)gB0, pb1 = *(const uint4*)(gB0 + 4);
    uint4 pb2 = *(const uint4*)gB1, pb3 = *(const uint4*)(gB1 + 4);

    f32x4 acc1[4][4], acc2[4][4];
    const f32x4 z4 = {0.f, 0.f, 0.f, 0.f};
#pragma unroll
    for (int i = 0; i < 4; ++i)
#pragma unroll
        for (int j = 0; j < 4; ++j) { acc1[i][j] = z4; acc2[i][j] = z4; }

    for (int k0 = 0; k0 < 1024; k0 += 32) {
        __syncthreads();
        write_split(&Ab[mtA][0][flA][0],     &Ab[mtA][1][flA][0],     pa0, pa1);
        write_split(&Ab[mtA + 4][0][flA][0], &Ab[mtA + 4][1][flA][0], pa2, pa3);
        write_split(&Bb[mtA][0][flA][0],     &Bb[mtA][1][flA][0],     pb0, pb1);
        write_split(&Bb[mtA + 4][0][flA][0], &Bb[mtA + 4][1][flA][0], pb2, pb3);
        __syncthreads();
        if (k0 < 992) {
            int kn = k0 + 32;
            pa0 = *(const uint4*)(gA0 + kn); pa1 = *(const uint4*)(gA0 + kn + 4);
            pa2 = *(const uint4*)(gA1 + kn); pa3 = *(const uint4*)(gA1 + kn + 4);
            pb0 = *(const uint4*)(gB0 + kn); pb1 = *(const uint4*)(gB0 + kn + 4);
            pb2 = *(const uint4*)(gB1 + kn); pb3 = *(const uint4*)(gB1 + kn + 4);
        }
        half8 ah[4], al[4];
#pragma unroll
        for (int mt = 0; mt < 4; ++mt) {
            ah[mt] = *(half8*)&Ab[wm + mt][0][lane][0];
            al[mt] = *(half8*)&Ab[wm + mt][1][lane][0];
        }
#pragma unroll
        for (int nt = 0; nt < 4; ++nt) {
            half8 bh = *(half8*)&Bb[wn + nt][0][lane][0];
            half8 bl = *(half8*)&Bb[wn + nt][1][lane][0];
#pragma unroll
            for (int mt = 0; mt < 4; ++mt) {
                acc1[mt][nt] = MFMA16(ah[mt], bh, acc1[mt][nt], 0, 0, 0);
                acc2[mt][nt] = MFMA16(ah[mt], bl, acc2[mt][nt], 0, 0, 0);
                acc2[mt][nt] = MFMA16(al[mt], bh, acc2[mt][nt], 0, 0, 0);
            }
        }
    }
    const int b_ = n0 >> 11, t0 = n0 & 2047;
#pragma unroll
    for (int mt = 0; mt < 4; ++mt) {
#pragma unroll
        for (int r_ = 0; r_ < 4; ++r_) {
            int m = m0 + (wm + mt) * 16 + quad * 4 + r_;
            float bs = bias[m];
            float* orow = &outp[(size_t)(b_ * 1024 + m) * 2048 + t0];
#pragma unroll
            for (int nt = 0; nt < 4; ++nt) {
                float val = acc1[mt][nt][r_] + acc2[mt][nt][r_] * (1.f / 2048.f) + bs;
                orow[(wn + nt) * 16 + l15] = val;
            }
        }
    }
}

// ------------------------------------------------------------- FFT + filter
__global__ __launch_bounds__(256) void k_fft_filter(
    float* __restrict__ qT, float* __restrict__ kT, float* __restrict__ vT,
    float* __restrict__ qiT, float* __restrict__ kiT,
    const float2* __restrict__ tw, const float2* __restrict__ filt)
{
    __shared__ float2 sf[2048];
    const int bid = blockIdx.x;          // 0..6143
    const int mat = bid >> 11;
    const int seq = bid & 2047;
    float* base = (mat == 0) ? qT : (mat == 1) ? kT : vT;
    float* src = base + (size_t)seq * 2048;
    const int tid = threadIdx.x;

    for (int i = tid; i < 2048; i += 256) {
        int j = (int)(__brev((unsigned)i) >> 21);
        sf[j] = make_float2(src[i], 0.f);
    }
    __syncthreads();
    for (int st = 1; st <= 11; ++st) {
        const int half = 1 << (st - 1);
        const int shift = 11 - st;
        for (int u = tid; u < 1024; u += 256) {
            int pos = u & (half - 1);
            int bi = 2 * u - pos;
            float2 w = tw[pos << shift];
            float2 a = sf[bi], b = sf[bi + half];
            float tr = w.x * b.x - w.y * b.y;
            float ti = w.x * b.y + w.y * b.x;
            sf[bi]        = make_float2(a.x + tr, a.y + ti);
            sf[bi + half] = make_float2(a.x - tr, a.y - ti);
        }
        __syncthreads();
    }
    unsigned* dst_re = (unsigned*)src;
    unsigned* dst_im = (mat == 0) ? (unsigned*)(qiT + (size_t)seq * 2048)
                                  : (unsigned*)(kiT + (size_t)seq * 2048);
    for (int i = tid; i < 2048; i += 256) {
        float2 z = sf[i];
        float2 f = filt[i];
        float re = z.x * f.x - z.y * f.y;
        float im = z.x * f.y + z.y * f.x;
        if (mat == 0) {
            dst_re[i] = pack_split(0.125f * re);
            dst_im[i] = pack_split(0.125f * im);
        } else if (mat == 1) {
            dst_re[i] = pack_split(re);
            dst_im[i] = pack_split(-im);
        } else {
            dst_re[i] = pack_split(re);
        }
    }
}

// ------------------------------------------------------------- flash (MFMA f16)
__global__ __launch_bounds__(512) void k_flash(
    const unsigned* __restrict__ qpk, const unsigned* __restrict__ qipk,
    const unsigned* __restrict__ kpk, const unsigned* __restrict__ kipk,
    const unsigned* __restrict__ vpk, unsigned* __restrict__ attpk)
{
    __shared__ __align__(16) _Float16 Kbuf[2][4][2][64][8];  // 16KB
    __shared__ __align__(16) _Float16 Vbuf[4][2][64][8];     //  8KB
    __shared__ __align__(16) _Float16 Pbuf[8][16][32];       //  8KB

    const int tid = threadIdx.x;
    const int w = tid >> 6, lane = tid & 63;
    const int quad = lane >> 4, l15 = lane & 15;
    const int bh = blockIdx.x >> 4, tb = blockIdx.x & 15;
    const size_t bc = (size_t)bh * 64;
    const int tw0 = tb * 128 + w * 16;

    half8 aqh[4], aql[4];
#pragma unroll
    for (int kc = 0; kc < 4; ++kc) {
#pragma unroll
        for (int j = 0; j < 8; ++j) {
            int d = kc * 32 + quad * 8 + j;
            int t = tw0 + l15;
            unsigned u = (d < 64) ? qpk[(bc + d) * 2048 + t]
                                  : qipk[(bc + d - 64) * 2048 + t];
            aqh[kc][j] = lo16(u);
            aql[kc][j] = hi16(u);
        }
    }

    f32x4 O1[4], O2[4];
    const f32x4 zero4 = {0.f, 0.f, 0.f, 0.f};
#pragma unroll
    for (int nt = 0; nt < 4; ++nt) { O1[nt] = zero4; O2[nt] = zero4; }
    float m_[4] = {-3e38f, -3e38f, -3e38f, -3e38f};
    float l_[4] = {0.f, 0.f, 0.f, 0.f};

    const int sK = tid & 31, dcK = tid >> 5;
    const int stK = sK >> 4, kcK = dcK >> 2, qK = dcK & 3;
    const int laneK = (sK & 15) + qK * 16;
    const int sV = tid & 31, dcV = tid >> 5;

    for (int s0 = 0; s0 < 2048; s0 += 32) {
        __syncthreads();
        {
            half8 kh, kl;
#pragma unroll
            for (int j = 0; j < 8; ++j) {
                int d = dcK * 8 + j;
                unsigned u = (d < 64) ? kpk[(bc + d) * 2048 + s0 + sK]
                                      : kipk[(bc + d - 64) * 2048 + s0 + sK];
                kh[j] = lo16(u);
                kl[j] = hi16(u);
            }
            *(half8*)&Kbuf[stK][kcK][0][laneK][0] = kh;
            *(half8*)&Kbuf[stK][kcK][1][laneK][0] = kl;
        }
        if (tid < 256) {
#pragma unroll
            for (int j = 0; j < 8; ++j) {
                int d = dcV * 8 + j;
                unsigned u = vpk[(bc + d) * 2048 + s0 + sV];
                int nt = d >> 4, ln = (d & 15) + (sV >> 3) * 16;
                Vbuf[nt][0][ln][sV & 7] = lo16(u);
                Vbuf[nt][1][ln][sV & 7] = hi16(u);
            }
        }
        __syncthreads();

        f32x4 S1[2], S2[2];
#pragma unroll
        for (int st = 0; st < 2; ++st) { S1[st] = zero4; S2[st] = zero4; }
#pragma unroll
        for (int st = 0; st < 2; ++st) {
#pragma unroll
            for (int kc = 0; kc < 4; ++kc) {
                half8 bhf = *(half8*)&Kbuf[st][kc][0][lane][0];
                half8 blf = *(half8*)&Kbuf[st][kc][1][lane][0];
                S1[st] = MFMA16(aqh[kc], bhf, S1[st], 0, 0, 0);
                S2[st] = MFMA16(aqh[kc], blf, S2[st], 0, 0, 0);
                S2[st] = MFMA16(aql[kc], bhf, S2[st], 0, 0, 0);
            }
        }

#pragma unroll
        for (int r = 0; r < 4; ++r) {
            float v0 = S1[0][r] + S2[0][r] * (1.f / 2048.f);
            float v1 = S1[1][r] + S2[1][r] * (1.f / 2048.f);
            float mt = fmaxf(v0, v1);
#pragma unroll
            for (int msk = 1; msk < 16; msk <<= 1)
                mt = fmaxf(mt, __shfl_xor(mt, msk, 16));
            float mn = fmaxf(m_[r], mt);
            float al = __expf(m_[r] - mn);
            m_[r] = mn;
            float p0 = __expf(v0 - mn);
            float p1 = __expf(v1 - mn);
            float rs = p0 + p1;
#pragma unroll
            for (int msk = 1; msk < 16; msk <<= 1)
                rs += __shfl_xor(rs, msk, 16);
            l_[r] = l_[r] * al + rs;
#pragma unroll
            for (int nt = 0; nt < 4; ++nt) { O1[nt][r] *= al; O2[nt][r] *= al; }
            int t = quad * 4 + r;
            Pbuf[w][t][l15]      = (_Float16)p0;
            Pbuf[w][t][l15 + 16] = (_Float16)p1;
        }

        half8 ap = *(half8*)&Pbuf[w][l15][quad * 8];
#pragma unroll
        for (int nt = 0; nt < 4; ++nt) {
            half8 vh = *(half8*)&Vbuf[nt][0][lane][0];
            half8 vl = *(half8*)&Vbuf[nt][1][lane][0];
            O1[nt] = MFMA16(ap, vh, O1[nt], 0, 0, 0);
            O2[nt] = MFMA16(ap, vl, O2[nt], 0, 0, 0);
        }
    }

    const int b = bh >> 4, h = bh & 15;
#pragma unroll
    for (int r = 0; r < 4; ++r) {
        float inv = 1.0f / l_[r];
        int t = tw0 + quad * 4 + r;
        size_t row = (size_t)b * 2048 + t;
#pragma unroll
        for (int nt = 0; nt < 4; ++nt) {
            float val = (O1[nt][r] + O2[nt][r] * (1.f / 2048.f)) * inv;
            attpk[row * 1024 + h * 64 + nt * 16 + l15] = pack_split(val);
        }
    }
}

// --------------------------------------------------- out GEMM (MFMA f16-split)
// out[t][c] = att @ wo + bo: M=t(4096), N=c_out(1024), K=1024.
// A = attpk[t][k], B = wopk[c_out][k].
__global__ __launch_bounds__(256) void k_gemm_out(
    const unsigned* __restrict__ attpk, const unsigned* __restrict__ wopk,
    const float* __restrict__ bo, float* __restrict__ out)
{
    __shared__ __align__(16) _Float16 Ab[8][2][64][8];
    __shared__ __align__(16) _Float16 Bb[8][2][64][8];
    const int tid = threadIdx.x;
    const int m0 = blockIdx.x * 128, n0 = blockIdx.y * 128;
    const int w = tid >> 6, lane = tid & 63, quad = lane >> 4, l15 = lane & 15;
    const int wm = (w & 1) * 4, wn = (w >> 1) * 4;

    const int chA = tid & 3, rA = tid >> 2;
    const int flA = (rA & 15) + 16 * chA, mtA = rA >> 4;
    const unsigned* gA0 = &attpk[(size_t)(m0 + rA) * 1024 + chA * 8];
    const unsigned* gA1 = gA0 + (size_t)64 * 1024;
    const unsigned* gB0 = &wopk[(size_t)(n0 + rA) * 1024 + chA * 8];
    const unsigned* gB1 = gB0 + (size_t)64 * 1024;

    uint4 pa0 = *(const uint4*)gA0, pa1 = *(const uint4*)(gA0 + 4);
    uint4 pa2 = *(const uint4*)gA1, pa3 = *(const uint4*)(gA1 + 4);
    uint4 pb0 = *(const uint4*)gB0, pb1 = *(const uint4*)(gB0 + 4);
    uint4 pb2 = *(const uint4*)gB1, pb3 = *(const uint4*)(gB1 + 4);

    f32x4 acc1[4][4], acc2[4][4];
    const f32x4 z4 = {0.f, 0.f, 0.f, 0.f};
#pragma unroll
    for (int i = 0; i < 4; ++i)
#pragma unroll
        for (int j = 0; j < 4; ++j) { acc1[i][j] = z4; acc2[i][j] = z4; }

    for (int k0 = 0; k0 < 1024; k0 += 32) {
        __syncthreads();
        write_split(&Ab[mtA][0][flA][0],     &Ab[mtA][1][flA][0],     pa0, pa1);
        write_split(&Ab[mtA + 4][0][flA][0], &Ab[mtA + 4][1][flA][0], pa2, pa3);
        write_split(&Bb[mtA][0][flA][0],     &Bb[mtA][1][flA][0],     pb0, pb1);
        write_split(&Bb[mtA + 4][0][flA][0], &Bb[mtA + 4][1][flA][0], pb2, pb3);
        __syncthreads();
        if (k0 < 992) {
            int kn = k0 + 32;
            pa0 = *(const uint4*)(gA0 + kn); pa1 = *(const uint4*)(gA0 + kn + 4);
            pa2 = *(const uint4*)(gA1 + kn); pa3 = *(const uint4*)(gA1 + kn + 4);
            pb0 = *(const uint4*)(gB0 + kn); pb1 = *(const uint4*)(gB0 + kn + 4);
            pb2 = *(const uint4*)(gB1 + kn); pb3 = *(const uint4*)(gB1 + kn + 4);
        }
        half8 ah[4], al[4];
#pragma unroll
        for (int mt = 0; mt < 4; ++mt) {
            ah[mt] = *(half8*)&Ab[wm + mt][0][lane][0];
            al[mt] = *(half8*)&Ab[wm + mt][1][lane][0];
        }
#pragma unroll
        for (int nt = 0; nt < 4; ++nt) {
            half8 bh = *(half8*)&Bb[wn + nt][0][lane][0];
            half8 bl = *(half8*)&Bb[wn + nt][1][lane][0];
#pragma unroll
            for (int mt = 0; mt < 4; ++mt) {
                acc1[mt][nt] = MFMA16(ah[mt], bh, acc1[mt][nt], 0, 0, 0);
                acc2[mt][nt] = MFMA16(ah[mt], bl, acc2[mt][nt], 0, 0, 0);
                acc2[mt][nt] = MFMA16(al[mt], bh, acc2[mt][nt], 0, 0, 0);
            }
        }
    }
#pragma unroll
    for (int mt = 0; mt < 4; ++mt) {
#pragma unroll
        for (int r_ = 0; r_ < 4; ++r_) {
            int m = m0 + (wm + mt) * 16 + quad * 4 + r_;
            float* orow = &out[(size_t)m * 1024 + n0];
#pragma unroll
            for (int nt = 0; nt < 4; ++nt) {
                int n = (wn + nt) * 16 + l15;
                float val = acc1[mt][nt][r_] + acc2[mt][nt][r_] * (1.f / 2048.f)
                          + bo[n0 + n];
                orow[n] = val;
            }
        }
    }
}

// ------------------------------------------------------------- energy renorm
__global__ __launch_bounds__(256) void k_norm(
    const float* __restrict__ x, float* __restrict__ out,
    const float* __restrict__ en)
{
    const int row = blockIdx.x;
    const int tid = threadIdx.x;
    const float* xr = x + (size_t)row * 1024;
    float* orow = out + (size_t)row * 1024;
    float4 xv = *(const float4*)&xr[tid * 4];
    float4 ov = *(const float4*)&orow[tid * 4];
    float ssx = xv.x * xv.x + xv.y * xv.y + xv.z * xv.z + xv.w * xv.w;
    float sso = ov.x * ov.x + ov.y * ov.y + ov.z * ov.z + ov.w * ov.w;
#pragma unroll
    for (int m = 1; m <= 32; m <<= 1) {
        ssx += __shfl_xor(ssx, m, 64);
        sso += __shfl_xor(sso, m, 64);
    }
    __shared__ float rx[4], ro[4];
    const int wid = tid >> 6;
    if ((tid & 63) == 0) { rx[wid] = ssx; ro[wid] = sso; }
    __syncthreads();
    float tsx = rx[0] + rx[1] + rx[2] + rx[3];
    float tso = ro[0] + ro[1] + ro[2] + ro[3];
    float scale = sqrtf(tsx) / (sqrtf(tso) + 1e-8f) * en[0];
    ov.x *= scale; ov.y *= scale; ov.z *= scale; ov.w *= scale;
    *(float4*)&orow[tid * 4] = ov;
}

// ------------------------------------------------------------- launch
extern "C" void kernel_launch(void* const* d_in, const int* in_sizes, int n_in,
                              void* d_out, int out_size, void* d_ws, size_t ws_size,
                              hipStream_t stream)
{
    const float* x     = (const float*)d_in[0];
    const float* fd    = (const float*)d_in[1];
    const float* wq    = (const float*)d_in[2];
    const float* bq    = (const float*)d_in[3];
    const float* wk    = (const float*)d_in[4];
    const float* bk    = (const float*)d_in[5];
    const float* wv    = (const float*)d_in[6];
    const float* bv    = (const float*)d_in[7];
    const float* wo    = (const float*)d_in[8];
    const float* bo    = (const float*)d_in[9];
    const float* alpha = (const float*)d_in[10];
    const float* fas   = (const float*)d_in[11];
    const float* en    = (const float*)d_in[12];
    float* out = (float*)d_out;
    float* ws  = (float*)d_ws;

    float* qT  = ws;                               // -> qpk -> wopk
    float* kT  = ws + (size_t)1 * 4194304;         // -> kpk
    float* vT  = ws + (size_t)2 * 4194304;         // -> vpk
    float* qiT = ws + (size_t)3 * 4194304;         // wqkv-pk -> qipk
    float* kiT = ws + (size_t)4 * 4194304;         // -> kipk
    float* att = ws + (size_t)5 * 4194304;         // xpk -> attpk
    float2* tw   = (float2*)(ws + (size_t)6 * 4194304);
    float2* filt = (float2*)(ws + (size_t)6 * 4194304 + 2048);

    unsigned* wqkvpk = (unsigned*)qiT;
    unsigned* xpk    = (unsigned*)att;
    unsigned* attpk  = (unsigned*)att;
    unsigned* wopk   = (unsigned*)qT;

    k_init_tables<<<8, 256, 0, stream>>>(tw, filt, fd, alpha, fas);
    k_prep_w<<<dim3(16, 16), 256, 0, stream>>>(wq, wqkvpk);
    k_prep_w<<<dim3(16, 16), 256, 0, stream>>>(wk, wqkvpk + 1048576);
    k_prep_w<<<dim3(16, 16), 256, 0, stream>>>(wv, wqkvpk + 2097152);
    k_prep_x<<<1024, 256, 0, stream>>>(x, xpk);
    k_gemm_qkv<<<dim3(8, 32, 3), 256, 0, stream>>>(xpk, wqkvpk, bq, bk, bv,
                                                   qT, kT, vT);
    k_fft_filter<<<6144, 256, 0, stream>>>(qT, kT, vT, qiT, kiT, tw, filt);
    k_flash<<<512, 512, 0, stream>>>((const unsigned*)qT, (const unsigned*)qiT,
                                     (const unsigned*)kT, (const unsigned*)kiT,
                                     (const unsigned*)vT, attpk);
    k_prep_w<<<dim3(16, 16), 256, 0, stream>>>(wo, wopk);
    k_gemm_out<<<dim3(32, 8), 256, 0, stream>>>(attpk, wopk, bo, out);
    k_norm<<<4096, 256, 0, stream>>>(x, out, en);
}